// Round 3
// baseline (4584.470 us; speedup 1.0000x reference)
//
#include <hip/hip_runtime.h>
#include <hip/hip_bf16.h>

#define B_ 16
#define T_ 750
#define TP 768
#define C_ 2048
#define K_ 50
#define KP 64
#define H_ 8
#define DH 256
#define NCLS 21
#define SCALE_ 0.0625f
#define FG_TOPK 93
#define BG_TOPK 250

// output offsets (f32 elements)
#define O_FG 0
#define O_BG 336
#define O_ATT 672
#define O_CAS 24672
#define O_FGC 276672
#define O_BGC 528672
#define O_UNC 780672

typedef __hip_bfloat16 bf16;
typedef __attribute__((ext_vector_type(8))) short short8;
typedef __attribute__((ext_vector_type(4))) float f32x4;

__device__ __forceinline__ void gld16(bf16* lds, const bf16* g) {
  __builtin_amdgcn_global_load_lds(
      (const __attribute__((address_space(1))) unsigned int*)g,
      (__attribute__((address_space(3))) unsigned int*)lds, 16, 0, 0);
}

#define EPI_RAW 0
#define EPI_BIAS 1
#define EPI_BIAS_RELU 2
#define EPI_BN 3

// NT GEMM: C[M,N] = A[M,K] * B[N,K]^T  (both row-major bf16, K contiguous)
// AMODE 1: A addressing for the 3-tap conv over Xc[B][770][C_]
// z offsets: ptr += (z/zdiv)*s1 + (z%zdiv)*s2
template<int EPI, int AMODE>
__global__ __launch_bounds__(256)
void gemm_nt(const bf16* __restrict__ A, int lda, long long sA1, long long sA2,
             const bf16* __restrict__ B, int ldb, long long sB1, long long sB2,
             bf16* __restrict__ C, int ldc, long long sC1, long long sC2,
             int Ksize, int zdiv,
             const float* __restrict__ bias,
             const float* __restrict__ bng, const float* __restrict__ bnb,
             const float* __restrict__ bnm, const float* __restrict__ bnv)
{
  __shared__ __align__(16) bf16 As[128 * 32];
  __shared__ __align__(16) bf16 Bs[128 * 32];
  const int tid  = threadIdx.x;
  const int lane = tid & 63;
  const int wave = tid >> 6;
  const int row0 = blockIdx.y * 128;
  const int col0 = blockIdx.x * 128;
  const int z    = blockIdx.z;
  A += (size_t)(z / zdiv) * sA1 + (size_t)(z % zdiv) * sA2;
  B += (size_t)(z / zdiv) * sB1 + (size_t)(z % zdiv) * sB2;
  C += (size_t)(z / zdiv) * sC1 + (size_t)(z % zdiv) * sC2;
  const int wm = (wave & 1) * 64;
  const int wn = (wave >> 1) * 64;
  const int fm = lane & 15;
  const int fq = lane >> 4;
  const int bIdx = row0 / TP;       // batch index for AMODE 1 (tiles never straddle b)

  f32x4 acc[4][4] = {};

  const int r0 = tid >> 2;          // staging chunk row (chunk = 16B = 8 bf16)
  const int c0 = (tid & 3) << 3;    // staging chunk col (elements)

  for (int k0 = 0; k0 < Ksize; k0 += 32) {
    const bf16* aB;
    if (AMODE == 1) {
      int kk = k0 >> 11;            // conv tap 0..2
      int ck = k0 & 2047;           // col within tap
      aB = A + (size_t)(row0 + 2 * bIdx + kk) * lda + ck;
    } else {
      aB = A + (size_t)row0 * lda + k0;
    }
    const bf16* bB = B + (size_t)col0 * ldb + k0;
    gld16(&As[tid * 8],         aB + (size_t)r0 * lda + c0);
    gld16(&As[(tid + 256) * 8], aB + (size_t)(r0 + 64) * lda + c0);
    gld16(&Bs[tid * 8],         bB + (size_t)r0 * ldb + c0);
    gld16(&Bs[(tid + 256) * 8], bB + (size_t)(r0 + 64) * ldb + c0);
    __syncthreads();
    short8 af[4], bfr[4];
    #pragma unroll
    for (int mi = 0; mi < 4; mi++)
      af[mi] = *(const short8*)&As[(wm + mi * 16 + fm) * 32 + fq * 8];
    #pragma unroll
    for (int ni = 0; ni < 4; ni++)
      bfr[ni] = *(const short8*)&Bs[(wn + ni * 16 + fm) * 32 + fq * 8];
    #pragma unroll
    for (int mi = 0; mi < 4; mi++)
      #pragma unroll
      for (int ni = 0; ni < 4; ni++)
        acc[mi][ni] = __builtin_amdgcn_mfma_f32_16x16x32_bf16(af[mi], bfr[ni], acc[mi][ni], 0, 0, 0);
    __syncthreads();
  }

  #pragma unroll
  for (int mi = 0; mi < 4; mi++) {
    const int gr0 = row0 + wm + mi * 16 + fq * 4;
    #pragma unroll
    for (int ni = 0; ni < 4; ni++) {
      const int gc = col0 + wn + ni * 16 + fm;
      float bia = 0.f, sc = 0.f, sh = 0.f;
      if (EPI == EPI_BIAS || EPI == EPI_BIAS_RELU || EPI == EPI_BN)
        bia = bias[gc];
      if (EPI == EPI_BN) {
        sc = bng[gc] * rsqrtf(bnv[gc] + 1e-5f);
        sh = bnb[gc] - bnm[gc] * sc;
      }
      #pragma unroll
      for (int r = 0; r < 4; r++) {
        size_t idx = (size_t)(gr0 + r) * ldc + gc;
        float v = acc[mi][ni][r];
        if (EPI == EPI_BIAS_RELU) {
          C[idx] = __float2bfloat16(fmaxf(v + bia, 0.f));
        } else if (EPI == EPI_BIAS) {
          C[idx] = __float2bfloat16(v + bia);
        } else if (EPI == EPI_RAW) {
          C[idx] = __float2bfloat16(v);
        } else {
          float res = __bfloat162float(C[idx]) + (v + bia) * sc + sh;
          C[idx] = __float2bfloat16(res);
        }
      }
    }
  }
}

// f32 -> bf16 elementwise (n divisible by 1024)
__global__ __launch_bounds__(256) void cvt_f32_bf16(const float* __restrict__ src, bf16* __restrict__ dst, int n) {
  int i = (blockIdx.x * 256 + threadIdx.x) * 4;
  if (i + 3 < n) {
    float4 v = *(const float4*)&src[i];
    dst[i]     = __float2bfloat16(v.x);
    dst[i + 1] = __float2bfloat16(v.y);
    dst[i + 2] = __float2bfloat16(v.z);
    dst[i + 3] = __float2bfloat16(v.w);
  }
}

// pack conv weight: Wcv[o][kk*2048 + c] = emb_w[o][c][kk]  (f32 -> bf16)
__global__ __launch_bounds__(256) void pack_wconv(const float* __restrict__ w, bf16* __restrict__ out) {
  int idx = blockIdx.x * 256 + threadIdx.x;
  int o = idx / (3 * C_), k = idx % (3 * C_);
  int kk = k >> 11, c = k & 2047;
  out[idx] = __float2bfloat16(w[((size_t)o * C_ + c) * 3 + kk]);
}

// Xc[b][r][c]: r=1+t for t in [0,750), zeros elsewhere (rows 0, 751..769)  (f32 -> bf16)
__global__ __launch_bounds__(256) void pack_xc(const float* __restrict__ X, bf16* __restrict__ Xc) {
  int idx = blockIdx.x * 256 + threadIdx.x;
  int c = idx & 2047;
  int rb = idx >> 11;
  int b = rb / 770, r = rb % 770;
  int t = r - 1;
  float v = 0.f;
  if (t >= 0 && t < T_) v = X[((size_t)b * T_ + t) * C_ + c];
  Xc[idx] = __float2bfloat16(v);
}

__global__ __launch_bounds__(256) void mask_kernel(const int* __restrict__ bbox, const int* __restrict__ cntp,
                                                   unsigned long long* __restrict__ pb, float* __restrict__ rcnt) {
  int b = blockIdx.x;
  __shared__ int ss[K_], se[K_];
  int cnt = cntp[b];
  if (threadIdx.x < K_) {
    ss[threadIdx.x] = bbox[(b * K_ + threadIdx.x) * 2];
    se[threadIdx.x] = bbox[(b * K_ + threadIdx.x) * 2 + 1];
  }
  __syncthreads();
  for (int t = threadIdx.x; t < TP; t += 256) {
    unsigned long long bits = 0; int cov = 0;
    for (int k = 0; k < cnt; k++)
      if (ss[k] <= t && t <= se[k]) { bits |= 1ull << k; cov++; }
    pb[b * TP + t] = bits;
    rcnt[b * TP + t] = (float)cov;
  }
}

// per-b: SIM is [H][TP][TP]; pbr = pb + b*TP
__global__ __launch_bounds__(256) void softmax_intra(bf16* __restrict__ SIM, const unsigned long long* __restrict__ pbr) {
  __shared__ float red[4];
  int t = blockIdx.x % TP;
  int h = blockIdx.x / TP;
  bf16* row = SIM + ((size_t)h * TP + t) * TP;
  unsigned long long pt = pbr[t];
  int tid = threadIdx.x;
  float x[3];
  #pragma unroll
  for (int i = 0; i < 3; i++) {
    int s = tid + i * 256;
    bool ok = (pbr[s] & pt) != 0ull;
    x[i] = ok ? __bfloat162float(row[s]) * SCALE_ : -1e30f;
  }
  float mx = fmaxf(fmaxf(x[0], x[1]), x[2]);
  #pragma unroll
  for (int o = 32; o; o >>= 1) mx = fmaxf(mx, __shfl_down(mx, o));
  if ((tid & 63) == 0) red[tid >> 6] = mx;
  __syncthreads();
  mx = fmaxf(fmaxf(red[0], red[1]), fmaxf(red[2], red[3]));
  __syncthreads();
  if (mx <= -1e29f) {  // fully masked row -> nan_to_num -> zeros
    #pragma unroll
    for (int i = 0; i < 3; i++) row[tid + i * 256] = __float2bfloat16(0.f);
    return;
  }
  float e[3], s = 0.f;
  #pragma unroll
  for (int i = 0; i < 3; i++) {
    e[i] = (x[i] <= -1e29f) ? 0.f : __expf(x[i] - mx);
    s += e[i];
  }
  #pragma unroll
  for (int o = 32; o; o >>= 1) s += __shfl_down(s, o);
  if ((tid & 63) == 0) red[tid >> 6] = s;
  __syncthreads();
  s = red[0] + red[1] + red[2] + red[3];
  float inv = 1.f / s;
  #pragma unroll
  for (int i = 0; i < 3; i++) row[tid + i * 256] = __float2bfloat16(e[i] * inv);
}

// per-b: V[TP][C_] -> Vt[C_][TP]
__global__ __launch_bounds__(256) void transpose_bt(const bf16* __restrict__ V, bf16* __restrict__ Vt) {
  __shared__ bf16 tile[32][33];
  int cb = blockIdx.x * 32, tb = blockIdx.y * 32;
  int tx = threadIdx.x & 31, ty = threadIdx.x >> 5;
  #pragma unroll
  for (int i = ty; i < 32; i += 8)
    tile[i][tx] = V[(size_t)(tb + i) * C_ + cb + tx];
  __syncthreads();
  #pragma unroll
  for (int i = ty; i < 32; i += 8)
    Vt[(size_t)(cb + i) * TP + tb + tx] = tile[tx][i];
}

__global__ __launch_bounds__(256) void seg_pool(const bf16* __restrict__ E, const int* __restrict__ bbox,
                                                const int* __restrict__ cntp, bf16* __restrict__ SEG) {
  int b = blockIdx.x >> 6, k = blockIdx.x & 63;
  int cnt = cntp[b];
  bf16* out = SEG + ((size_t)b * KP + k) * C_;
  if (k >= cnt) {
    for (int c = threadIdx.x; c < C_; c += 256) out[c] = __float2bfloat16(0.f);
    return;
  }
  int s = bbox[(b * K_ + k) * 2], e = bbox[(b * K_ + k) * 2 + 1];
  float inv = 1.f / (float)(e - s + 1);
  const bf16* Eb = E + (size_t)b * TP * C_;
  for (int c = threadIdx.x; c < C_; c += 256) {
    float acc = 0.f;
    for (int t = s; t <= e; t++) acc += __bfloat162float(Eb[(size_t)t * C_ + c]);
    out[c] = __float2bfloat16(acc * inv);
  }
}

// 48 KB LDS: Q (then V) staged; K read from global (L1/L2-resident slice)
__global__ __launch_bounds__(256) void inter_attn(const bf16* __restrict__ SQ, const bf16* __restrict__ SK,
                                                  const bf16* __restrict__ SV, const int* __restrict__ cntp,
                                                  bf16* __restrict__ SO) {
  __shared__ bf16 sQ[KP * DH];
  __shared__ float sP[KP * KP];
  int b = blockIdx.x >> 3, h = blockIdx.x & 7;
  int cnt = cntp[b];
  int tid = threadIdx.x;
  size_t base = (size_t)b * KP * C_ + (size_t)h * DH;
  for (int i = tid; i < KP * DH; i += 256) {
    int k = i >> 8, d = i & 255;
    sQ[i] = SQ[base + (size_t)k * C_ + d];
  }
  __syncthreads();
  for (int p = tid; p < KP * KP; p += 256) {
    int k = p >> 6, kk = p & 63;
    const bf16* Kr = SK + base + (size_t)kk * C_;
    float acc = 0.f;
    for (int d = 0; d < DH; d++)
      acc += __bfloat162float(sQ[k * DH + d]) * __bfloat162float(Kr[d]);
    sP[p] = (k < cnt && kk < cnt) ? acc * SCALE_ : -1e30f;
  }
  __syncthreads();
  if (tid < KP) {
    float* pr = sP + tid * KP;
    if (tid >= cnt) {
      for (int kk = 0; kk < KP; kk++) pr[kk] = 0.f;
    } else {
      float m = -1e30f;
      for (int kk = 0; kk < KP; kk++) m = fmaxf(m, pr[kk]);
      float s = 0.f;
      for (int kk = 0; kk < KP; kk++) {
        float e = (pr[kk] <= -1e29f) ? 0.f : __expf(pr[kk] - m);
        pr[kk] = e; s += e;
      }
      float inv = 1.f / s;
      for (int kk = 0; kk < KP; kk++) pr[kk] *= inv;
    }
  }
  __syncthreads();
  for (int i = tid; i < KP * DH; i += 256) {  // reuse sQ for V
    int k = i >> 8, d = i & 255;
    sQ[i] = SV[base + (size_t)k * C_ + d];
  }
  __syncthreads();
  for (int i = tid; i < KP * DH; i += 256) {
    int k = i >> 8, d = i & 255;
    float acc = 0.f;
    for (int kk = 0; kk < KP; kk++)
      acc += sP[k * KP + kk] * __bfloat162float(sQ[kk * DH + d]);
    SO[base + (size_t)k * C_ + d] = __float2bfloat16(acc);
  }
}

__global__ __launch_bounds__(256) void scatter_seg(const bf16* __restrict__ SO, const int* __restrict__ bbox,
                                                   const int* __restrict__ cntp, const float* __restrict__ rcnt,
                                                   bf16* __restrict__ OUTG) {
  __shared__ int klist[K_];
  __shared__ int nk;
  int b = blockIdx.x / TP, t = blockIdx.x % TP;
  int cnt = cntp[b];
  if (threadIdx.x == 0) {
    int n = 0;
    for (int k = 0; k < cnt; k++) {
      int s = bbox[(b * K_ + k) * 2], e = bbox[(b * K_ + k) * 2 + 1];
      if (s <= t && t <= e) klist[n++] = k;
    }
    nk = n;
  }
  __syncthreads();
  float inv = 1.f / fmaxf(rcnt[b * TP + t], 1e-5f);
  const bf16* Sb = SO + (size_t)b * KP * C_;
  bf16* out = OUTG + ((size_t)b * TP + t) * C_;
  int n = nk;
  for (int c = threadIdx.x; c < C_; c += 256) {
    float acc = 0.f;
    for (int i = 0; i < n; i++) acc += __bfloat162float(Sb[(size_t)klist[i] * C_ + c]);
    out[c] = __float2bfloat16(acc * inv);
  }
}

__global__ __launch_bounds__(256) void heads(const bf16* __restrict__ E,
    const float* __restrict__ att_w, const float* __restrict__ att_b,
    const float* __restrict__ cls_w, const float* __restrict__ cls_b,
    const float* __restrict__ unc_w,
    float* __restrict__ fgc, float* __restrict__ bgc, float* __restrict__ out) {
  __shared__ float part[24][4];
  int b = blockIdx.x / T_, t = blockIdx.x % T_;
  int tid = threadIdx.x, lane = tid & 63, wv = tid >> 6;
  const bf16* e = E + ((size_t)b * TP + t) * C_;
  int c0 = tid * 8;
  float vals[24];
  #pragma unroll
  for (int o = 0; o < 24; o++) vals[o] = 0.f;
  #pragma unroll
  for (int i = 0; i < 8; i++) {
    float x = __bfloat162float(e[c0 + i]);
    vals[0] += x * att_w[c0 + i];
    vals[1] += x * att_w[C_ + c0 + i];
    vals[2] += x * unc_w[c0 + i];
    #pragma unroll
    for (int o = 0; o < NCLS; o++)
      vals[3 + o] += x * cls_w[(size_t)(c0 + i) * NCLS + o];
  }
  #pragma unroll
  for (int o = 0; o < 24; o++) {
    float v = vals[o];
    #pragma unroll
    for (int off = 32; off; off >>= 1) v += __shfl_down(v, off);
    if (lane == 0) part[o][wv] = v;
  }
  __syncthreads();
  if (tid == 0) {
    float s[24];
    #pragma unroll
    for (int o = 0; o < 24; o++) s[o] = part[o][0] + part[o][1] + part[o][2] + part[o][3];
    size_t bt = (size_t)b * T_ + t;
    float v0 = s[0] + att_b[0];
    float v1 = s[1] + att_b[1];
    float m = fmaxf(v0, v1);
    float e0 = __expf(v0 - m), e1 = __expf(v1 - m);
    float p0 = e0 / (e0 + e1), p1 = e1 / (e0 + e1);
    out[O_ATT + bt * 2]     = p0;
    out[O_ATT + bt * 2 + 1] = p1;
    out[O_UNC + bt]         = s[2];
    float cas[NCLS], fg[NCLS], bg[NCLS];
    for (int o = 0; o < NCLS; o++) {
      cas[o] = s[3 + o] + cls_b[o];
      fg[o] = cas[o] * p0;
      bg[o] = cas[o] * p1;
      fgc[bt * NCLS + o] = fg[o];
      bgc[bt * NCLS + o] = bg[o];
    }
    auto smax = [&](const float* v, float* dst) {
      float mm = v[0];
      for (int o = 1; o < NCLS; o++) mm = fmaxf(mm, v[o]);
      float ss = 0.f; float ee[NCLS];
      for (int o = 0; o < NCLS; o++) { ee[o] = __expf(v[o] - mm); ss += ee[o]; }
      float iv = 1.f / ss;
      for (int o = 0; o < NCLS; o++) dst[o] = ee[o] * iv;
    };
    smax(cas, out + O_CAS + bt * NCLS);
    smax(fg,  out + O_FGC + bt * NCLS);
    smax(bg,  out + O_BGC + bt * NCLS);
  }
}

// bitonic sort descending; arr[0..ksel) are the largest
__global__ __launch_bounds__(512) void topk_mean(const float* __restrict__ fgc, const float* __restrict__ bgc,
                                                 float* __restrict__ means) {
  __shared__ float arr[1024];
  __shared__ float red[8];
  int idx = blockIdx.x;
  int which = idx / (B_ * NCLS);
  int r = idx % (B_ * NCLS);
  int b = r / NCLS, n = r % NCLS;
  const float* src = which ? bgc : fgc;
  int ksel = which ? BG_TOPK : FG_TOPK;
  int tid = threadIdx.x;
  for (int i = tid; i < 1024; i += 512)
    arr[i] = (i < T_) ? src[((size_t)b * T_ + i) * NCLS + n] : -1e30f;
  __syncthreads();
  for (int k = 2; k <= 1024; k <<= 1)
    for (int j = k >> 1; j > 0; j >>= 1) {
      for (int i = tid; i < 1024; i += 512) {
        int ixj = i ^ j;
        if (ixj > i) {
          bool up = ((i & k) == 0);
          float x = arr[i], y = arr[ixj];
          if (up ? (x < y) : (x > y)) { arr[i] = y; arr[ixj] = x; }
        }
      }
      __syncthreads();
    }
  float s = 0.f;
  for (int i = tid; i < ksel; i += 512) s += arr[i];
  #pragma unroll
  for (int o = 32; o; o >>= 1) s += __shfl_down(s, o);
  if ((tid & 63) == 0) red[tid >> 6] = s;
  __syncthreads();
  if (tid == 0) {
    float tot = 0.f;
    for (int w = 0; w < 8; w++) tot += red[w];
    means[(which * B_ + b) * NCLS + n] = tot / (float)ksel;
  }
}

__global__ void final_cls(const float* __restrict__ means, float* __restrict__ out) {
  if (threadIdx.x != 0) return;
  int which = blockIdx.x >> 4, b = blockIdx.x & 15;
  const float* v = means + (which * B_ + b) * NCLS;
  float m = v[0];
  for (int o = 1; o < NCLS; o++) m = fmaxf(m, v[o]);
  float s = 0.f; float e[NCLS];
  for (int o = 0; o < NCLS; o++) { e[o] = __expf(v[o] - m); s += e[o]; }
  float iv = 1.f / s;
  float* dst = out + (which ? O_BG : O_FG) + b * NCLS;
  for (int o = 0; o < NCLS; o++) dst[o] = e[o] * iv;
}

extern "C" void kernel_launch(void* const* d_in, const int* in_sizes, int n_in,
                              void* d_out, int out_size, void* d_ws, size_t ws_size,
                              hipStream_t stream) {
  const float* X     = (const float*)d_in[0];
  const int*   bbox  = (const int*)d_in[1];
  const int*   cntp  = (const int*)d_in[2];
  const float* emb_w = (const float*)d_in[3];
  const float* emb_b = (const float*)d_in[4];
  const float* i_qw  = (const float*)d_in[5];
  const float* i_qb  = (const float*)d_in[6];
  const float* i_kw  = (const float*)d_in[7];
  const float* i_kb  = (const float*)d_in[8];
  const float* i_vw  = (const float*)d_in[9];
  const float* i_vb  = (const float*)d_in[10];
  const float* i_ow  = (const float*)d_in[11];
  const float* i_ob  = (const float*)d_in[12];
  const float* i_bng = (const float*)d_in[13];
  const float* i_bnb = (const float*)d_in[14];
  const float* i_bnm = (const float*)d_in[15];
  const float* i_bnv = (const float*)d_in[16];
  const float* e_qw  = (const float*)d_in[17];
  const float* e_qb  = (const float*)d_in[18];
  const float* e_kw  = (const float*)d_in[19];
  const float* e_kb  = (const float*)d_in[20];
  const float* e_vw  = (const float*)d_in[21];
  const float* e_vb  = (const float*)d_in[22];
  const float* e_ow  = (const float*)d_in[23];
  const float* e_ob  = (const float*)d_in[24];
  const float* e_bng = (const float*)d_in[25];
  const float* e_bnb = (const float*)d_in[26];
  const float* e_bnm = (const float*)d_in[27];
  const float* e_bnv = (const float*)d_in[28];
  const float* att_w = (const float*)d_in[29];
  const float* att_b = (const float*)d_in[30];
  const float* cls_w = (const float*)d_in[31];
  const float* cls_b = (const float*)d_in[32];
  const float* unc_w = (const float*)d_in[33];
  float* out = (float*)d_out;

  // -------- workspace layout (lifetime-aliased, total 197,263,360 B) --------
  const size_t SZ_E  = (size_t)B_ * TP * C_ * 2;   // 50,331,648
  const size_t SZ_A  = (size_t)B_ * 770 * C_ * 2;  // 50,462,720  Xc -> O -> OUTG
  const size_t SZ_W  = (size_t)C_ * 3 * C_ * 2;    // 25,165,824  Wcv -> SIM/Vt/pb/rcnt/means
  const size_t SZ_P  = (size_t)4 * C_ * C_ * 2;    // 33,554,432  bf16 proj weights (i_, then e_)
  const size_t SZ_Q4 = (size_t)4 * TP * C_ * 2;    // 12,582,912  quarter-batch
  const size_t NEED  = SZ_E + SZ_A + SZ_W + SZ_P + 3 * SZ_Q4;
  if (ws_size < NEED) return;   // diagnostic: out stays zero

  char* ws  = (char*)d_ws;
  bf16* E   = (bf16*)ws;
  char* rA  = ws + SZ_E;
  char* rW  = rA + SZ_A;
  char* rP  = rW + SZ_W;
  char* rQ  = rP + SZ_P;
  char* rK  = rQ + SZ_Q4;
  char* rV  = rK + SZ_Q4;

  bf16* Xc   = (bf16*)rA;          // dead after conv GEMM
  bf16* O    = (bf16*)rA;          // PV output (intra attention)
  bf16* OUTG = (bf16*)rA;          // scatter output (O dead by then)
  bf16* Wcv  = (bf16*)rW;          // dead after conv GEMM
  bf16* SIMb = (bf16*)rW;                                        // 9,437,184
  bf16* Vtb  = (bf16*)(rW + 9437184);                            // 3,145,728
  unsigned long long* pb = (unsigned long long*)(rW + 12582912); // 98,304
  float* rcnt  = (float*)(rW + 12681216);                        // 49,152
  float* means = (float*)(rW + 12730368);                        // 2,688
  bf16* Wq = (bf16*)rP;
  bf16* Wk = Wq + (size_t)C_ * C_;
  bf16* Wv = Wk + (size_t)C_ * C_;
  bf16* Wo = Wv + (size_t)C_ * C_;
  bf16* Qh = (bf16*)rQ;
  bf16* Kh = (bf16*)rK;
  bf16* Vh = (bf16*)rV;
  // after intra attention: Qh/Kh dead -> segment buffers (20,971,520 B across rQ+rK)
  bf16* SEG = (bf16*)rQ;
  bf16* SQb = SEG + (size_t)B_ * KP * C_;
  bf16* SKb = SQb + (size_t)B_ * KP * C_;
  bf16* SVb = SKb + (size_t)B_ * KP * C_;
  bf16* SOb = SVb + (size_t)B_ * KP * C_;
  // after inter attention: Vh dead -> fgc/bgc
  float* fgc = (float*)rV;
  float* bgc = (float*)(rV + 1048576);

  const long long ZC = (long long)TP * C_;
  const long long ZS = (long long)TP * TP;
  const int NW = C_ * C_;  // 4,194,304

  pack_wconv<<<dim3((C_ * 3 * C_) / 256), 256, 0, stream>>>(emb_w, Wcv);
  pack_xc<<<dim3((B_ * 770 * C_) / 256), 256, 0, stream>>>(X, Xc);

  // emb = relu(conv1d(x) + b)   [Xc, Wcv die here]
  gemm_nt<EPI_BIAS_RELU, 1><<<dim3(C_ / 128, (B_ * TP) / 128, 1), 256, 0, stream>>>(
      Xc, C_, 0, 0, Wcv, 3 * C_, 0, 0, E, C_, 0, 0, 3 * C_, 1, emb_b, nullptr, nullptr, nullptr, nullptr);

  mask_kernel<<<dim3(B_), 256, 0, stream>>>(bbox, cntp, pb, rcnt);

  // convert intra projection weights f32 -> bf16
  cvt_f32_bf16<<<dim3(NW / 1024), 256, 0, stream>>>(i_qw, Wq, NW);
  cvt_f32_bf16<<<dim3(NW / 1024), 256, 0, stream>>>(i_kw, Wk, NW);
  cvt_f32_bf16<<<dim3(NW / 1024), 256, 0, stream>>>(i_vw, Wv, NW);
  cvt_f32_bf16<<<dim3(NW / 1024), 256, 0, stream>>>(i_ow, Wo, NW);

  // intra attention: quarter-batch QKV projection + per-b attention
  for (int q4 = 0; q4 < 4; q4++) {
    const bf16* Eq = E + (size_t)q4 * 4 * ZC;
    gemm_nt<EPI_BIAS, 0><<<dim3(C_ / 128, (4 * TP) / 128, 1), 256, 0, stream>>>(
        Eq, C_, 0, 0, Wq, C_, 0, 0, Qh, C_, 0, 0, C_, 1, i_qb, nullptr, nullptr, nullptr, nullptr);
    gemm_nt<EPI_BIAS, 0><<<dim3(C_ / 128, (4 * TP) / 128, 1), 256, 0, stream>>>(
        Eq, C_, 0, 0, Wk, C_, 0, 0, Kh, C_, 0, 0, C_, 1, i_kb, nullptr, nullptr, nullptr, nullptr);
    gemm_nt<EPI_BIAS, 0><<<dim3(C_ / 128, (4 * TP) / 128, 1), 256, 0, stream>>>(
        Eq, C_, 0, 0, Wv, C_, 0, 0, Vh, C_, 0, 0, C_, 1, i_vb, nullptr, nullptr, nullptr, nullptr);
    for (int lb = 0; lb < 4; lb++) {
      int b = q4 * 4 + lb;
      transpose_bt<<<dim3(C_ / 32, TP / 32, 1), 256, 0, stream>>>(Vh + (size_t)lb * ZC, Vtb);
      gemm_nt<EPI_RAW, 0><<<dim3(TP / 128, TP / 128, H_), 256, 0, stream>>>(
          Qh + (size_t)lb * ZC, C_, DH, 0, Kh + (size_t)lb * ZC, C_, DH, 0,
          SIMb, TP, ZS, 0, DH, 1, nullptr, nullptr, nullptr, nullptr, nullptr);
      softmax_intra<<<dim3(H_ * TP), 256, 0, stream>>>(SIMb, pb + (size_t)b * TP);
      gemm_nt<EPI_RAW, 0><<<dim3(DH / 128, TP / 128, H_), 256, 0, stream>>>(
          SIMb, TP, ZS, 0, Vtb, TP, (long long)DH * TP, 0,
          O + (size_t)b * ZC, C_, DH, 0, TP, 1, nullptr, nullptr, nullptr, nullptr, nullptr);
    }
  }
  // emb += BN(O @ i_ow^T + i_ob)   [Qh/Kh/Vh die here]
  gemm_nt<EPI_BN, 0><<<dim3(C_ / 128, (B_ * TP) / 128, 1), 256, 0, stream>>>(
      O, C_, 0, 0, Wo, C_, 0, 0, E, C_, 0, 0, C_, 1, i_ob, i_bng, i_bnb, i_bnm, i_bnv);

  // convert inter projection weights f32 -> bf16 (reuse slots)
  cvt_f32_bf16<<<dim3(NW / 1024), 256, 0, stream>>>(e_qw, Wq, NW);
  cvt_f32_bf16<<<dim3(NW / 1024), 256, 0, stream>>>(e_kw, Wk, NW);
  cvt_f32_bf16<<<dim3(NW / 1024), 256, 0, stream>>>(e_vw, Wv, NW);
  cvt_f32_bf16<<<dim3(NW / 1024), 256, 0, stream>>>(e_ow, Wo, NW);

  // inter-segment branch
  seg_pool<<<dim3(B_ * KP), 256, 0, stream>>>(E, bbox, cntp, SEG);
  gemm_nt<EPI_BIAS, 0><<<dim3(C_ / 128, (B_ * KP) / 128, 1), 256, 0, stream>>>(
      SEG, C_, 0, 0, Wq, C_, 0, 0, SQb, C_, 0, 0, C_, 1, e_qb, nullptr, nullptr, nullptr, nullptr);
  gemm_nt<EPI_BIAS, 0><<<dim3(C_ / 128, (B_ * KP) / 128, 1), 256, 0, stream>>>(
      SEG, C_, 0, 0, Wk, C_, 0, 0, SKb, C_, 0, 0, C_, 1, e_kb, nullptr, nullptr, nullptr, nullptr);
  gemm_nt<EPI_BIAS, 0><<<dim3(C_ / 128, (B_ * KP) / 128, 1), 256, 0, stream>>>(
      SEG, C_, 0, 0, Wv, C_, 0, 0, SVb, C_, 0, 0, C_, 1, e_vb, nullptr, nullptr, nullptr, nullptr);
  inter_attn<<<dim3(B_ * H_), 256, 0, stream>>>(SQb, SKb, SVb, cntp, SOb);
  scatter_seg<<<dim3(B_ * TP), 256, 0, stream>>>(SOb, bbox, cntp, rcnt, OUTG);
  gemm_nt<EPI_BN, 0><<<dim3(C_ / 128, (B_ * TP) / 128, 1), 256, 0, stream>>>(
      OUTG, C_, 0, 0, Wo, C_, 0, 0, E, C_, 0, 0, C_, 1, e_ob, e_bng, e_bnb, e_bnm, e_bnv);

  // heads + top-k + class softmaxes  [SEG.. dead; Vh region -> fgc/bgc]
  heads<<<dim3(B_ * T_), 256, 0, stream>>>(E, att_w, att_b, cls_w, cls_b, unc_w, fgc, bgc, out);
  topk_mean<<<dim3(2 * B_ * NCLS), 512, 0, stream>>>(fgc, bgc, means);
  final_cls<<<dim3(2 * B_), 64, 0, stream>>>(means, out);

  (void)in_sizes; (void)n_in; (void)out_size;
}

// Round 4
// 2657.988 us; speedup vs baseline: 1.7248x; 1.7248x over previous
//
#include <hip/hip_runtime.h>
#include <hip/hip_bf16.h>

#define B_ 16
#define T_ 750
#define TP 768
#define C_ 2048
#define K_ 50
#define KP 64
#define H_ 8
#define DH 256
#define NCLS 21
#define SCALE_ 0.0625f
#define FG_TOPK 93
#define BG_TOPK 250
#define C3 6144

// output offsets (f32 elements)
#define O_FG 0
#define O_BG 336
#define O_ATT 672
#define O_CAS 24672
#define O_FGC 276672
#define O_BGC 528672
#define O_UNC 780672

typedef __hip_bfloat16 bf16;
typedef __attribute__((ext_vector_type(8))) short short8;
typedef __attribute__((ext_vector_type(4))) float f32x4;

__device__ __forceinline__ void gld16(bf16* lds, const bf16* g) {
  __builtin_amdgcn_global_load_lds(
      (const __attribute__((address_space(1))) unsigned int*)g,
      (__attribute__((address_space(3))) unsigned int*)lds, 16, 0, 0);
}

#define EPI_RAW 0
#define EPI_BIAS 1
#define EPI_BIAS_RELU 2
#define EPI_BN 3

// NT GEMM: C[M,N] = A[M,K] * B[N,K]^T  (both row-major bf16, K contiguous)
// AMODE 1: A addressing for the 3-tap conv over Xc[B][770][C_]
// z offsets: ptr += (z/zdiv)*s1 + (z%zdiv)*s2
template<int EPI, int AMODE>
__global__ __launch_bounds__(256)
void gemm_nt(const bf16* __restrict__ A, int lda, long long sA1, long long sA2,
             const bf16* __restrict__ B, int ldb, long long sB1, long long sB2,
             bf16* __restrict__ C, int ldc, long long sC1, long long sC2,
             int Ksize, int zdiv,
             const float* __restrict__ bias,
             const float* __restrict__ bng, const float* __restrict__ bnb,
             const float* __restrict__ bnm, const float* __restrict__ bnv)
{
  __shared__ __align__(16) bf16 As[128 * 32];
  __shared__ __align__(16) bf16 Bs[128 * 32];
  const int tid  = threadIdx.x;
  const int lane = tid & 63;
  const int wave = tid >> 6;
  const int row0 = blockIdx.y * 128;
  const int col0 = blockIdx.x * 128;
  const int z    = blockIdx.z;
  A += (size_t)(z / zdiv) * sA1 + (size_t)(z % zdiv) * sA2;
  B += (size_t)(z / zdiv) * sB1 + (size_t)(z % zdiv) * sB2;
  C += (size_t)(z / zdiv) * sC1 + (size_t)(z % zdiv) * sC2;
  const int wm = (wave & 1) * 64;
  const int wn = (wave >> 1) * 64;
  const int fm = lane & 15;
  const int fq = lane >> 4;
  const int bIdx = row0 / TP;       // batch index for AMODE 1 (tiles never straddle b)

  f32x4 acc[4][4] = {};

  const int r0 = tid >> 2;          // staging chunk row (chunk = 16B = 8 bf16)
  const int c0 = (tid & 3) << 3;    // staging chunk col (elements)

  for (int k0 = 0; k0 < Ksize; k0 += 32) {
    const bf16* aB;
    if (AMODE == 1) {
      int kk = k0 >> 11;            // conv tap 0..2
      int ck = k0 & 2047;           // col within tap
      aB = A + (size_t)(row0 + 2 * bIdx + kk) * lda + ck;
    } else {
      aB = A + (size_t)row0 * lda + k0;
    }
    const bf16* bB = B + (size_t)col0 * ldb + k0;
    gld16(&As[tid * 8],         aB + (size_t)r0 * lda + c0);
    gld16(&As[(tid + 256) * 8], aB + (size_t)(r0 + 64) * lda + c0);
    gld16(&Bs[tid * 8],         bB + (size_t)r0 * ldb + c0);
    gld16(&Bs[(tid + 256) * 8], bB + (size_t)(r0 + 64) * ldb + c0);
    __syncthreads();
    short8 af[4], bfr[4];
    #pragma unroll
    for (int mi = 0; mi < 4; mi++)
      af[mi] = *(const short8*)&As[(wm + mi * 16 + fm) * 32 + fq * 8];
    #pragma unroll
    for (int ni = 0; ni < 4; ni++)
      bfr[ni] = *(const short8*)&Bs[(wn + ni * 16 + fm) * 32 + fq * 8];
    #pragma unroll
    for (int mi = 0; mi < 4; mi++)
      #pragma unroll
      for (int ni = 0; ni < 4; ni++)
        acc[mi][ni] = __builtin_amdgcn_mfma_f32_16x16x32_bf16(af[mi], bfr[ni], acc[mi][ni], 0, 0, 0);
    __syncthreads();
  }

  #pragma unroll
  for (int mi = 0; mi < 4; mi++) {
    const int gr0 = row0 + wm + mi * 16 + fq * 4;
    #pragma unroll
    for (int ni = 0; ni < 4; ni++) {
      const int gc = col0 + wn + ni * 16 + fm;
      float bia = 0.f, sc = 0.f, sh = 0.f;
      if (EPI == EPI_BIAS || EPI == EPI_BIAS_RELU || EPI == EPI_BN)
        bia = bias[gc];
      if (EPI == EPI_BN) {
        sc = bng[gc] * rsqrtf(bnv[gc] + 1e-5f);
        sh = bnb[gc] - bnm[gc] * sc;
      }
      #pragma unroll
      for (int r = 0; r < 4; r++) {
        size_t idx = (size_t)(gr0 + r) * ldc + gc;
        float v = acc[mi][ni][r];
        if (EPI == EPI_BIAS_RELU) {
          C[idx] = __float2bfloat16(fmaxf(v + bia, 0.f));
        } else if (EPI == EPI_BIAS) {
          C[idx] = __float2bfloat16(v + bia);
        } else if (EPI == EPI_RAW) {
          C[idx] = __float2bfloat16(v);
        } else {
          float res = __bfloat162float(C[idx]) + (v + bia) * sc + sh;
          C[idx] = __float2bfloat16(res);
        }
      }
    }
  }
}

// f32 -> bf16 elementwise (n divisible by 1024)
__global__ __launch_bounds__(256) void cvt_f32_bf16(const float* __restrict__ src, bf16* __restrict__ dst, int n) {
  int i = (blockIdx.x * 256 + threadIdx.x) * 4;
  if (i + 3 < n) {
    float4 v = *(const float4*)&src[i];
    dst[i]     = __float2bfloat16(v.x);
    dst[i + 1] = __float2bfloat16(v.y);
    dst[i + 2] = __float2bfloat16(v.z);
    dst[i + 3] = __float2bfloat16(v.w);
  }
}

// concat three C_-length f32 bias vectors
__global__ __launch_bounds__(256) void concat3(const float* __restrict__ a, const float* __restrict__ b,
                                               const float* __restrict__ c, float* __restrict__ dst) {
  int i = blockIdx.x * 256 + threadIdx.x;
  if (i < C_) { dst[i] = a[i]; dst[C_ + i] = b[i]; dst[2 * C_ + i] = c[i]; }
}

// pack conv weight: Wcv[o][kk*2048 + c] = emb_w[o][c][kk]  (f32 -> bf16)
__global__ __launch_bounds__(256) void pack_wconv(const float* __restrict__ w, bf16* __restrict__ out) {
  int idx = blockIdx.x * 256 + threadIdx.x;
  int o = idx / (3 * C_), k = idx % (3 * C_);
  int kk = k >> 11, c = k & 2047;
  out[idx] = __float2bfloat16(w[((size_t)o * C_ + c) * 3 + kk]);
}

// Xc[b][r][c]: r=1+t for t in [0,750), zeros elsewhere (rows 0, 751..769)  (f32 -> bf16)
__global__ __launch_bounds__(256) void pack_xc(const float* __restrict__ X, bf16* __restrict__ Xc) {
  int idx = blockIdx.x * 256 + threadIdx.x;
  int c = idx & 2047;
  int rb = idx >> 11;
  int b = rb / 770, r = rb % 770;
  int t = r - 1;
  float v = 0.f;
  if (t >= 0 && t < T_) v = X[((size_t)b * T_ + t) * C_ + c];
  Xc[idx] = __float2bfloat16(v);
}

__global__ __launch_bounds__(256) void mask_kernel(const int* __restrict__ bbox, const int* __restrict__ cntp,
                                                   unsigned long long* __restrict__ pb, float* __restrict__ rcnt) {
  int b = blockIdx.x;
  __shared__ int ss[K_], se[K_];
  int cnt = cntp[b];
  if (threadIdx.x < K_) {
    ss[threadIdx.x] = bbox[(b * K_ + threadIdx.x) * 2];
    se[threadIdx.x] = bbox[(b * K_ + threadIdx.x) * 2 + 1];
  }
  __syncthreads();
  for (int t = threadIdx.x; t < TP; t += 256) {
    unsigned long long bits = 0; int cov = 0;
    for (int k = 0; k < cnt; k++)
      if (ss[k] <= t && t <= se[k]) { bits |= 1ull << k; cov++; }
    pb[b * TP + t] = bits;
    rcnt[b * TP + t] = (float)cov;
  }
}

// quarter-batched: SIM4 is [4*H][TP][TP]; pb4 = pb + q*4*TP
__global__ __launch_bounds__(256) void softmax_intra(bf16* __restrict__ SIM4, const unsigned long long* __restrict__ pb4) {
  __shared__ float red[4];
  int t = blockIdx.x % TP;
  int zz = blockIdx.x / TP;             // 0..31 = b_local*8 + h
  bf16* row = SIM4 + ((size_t)zz * TP + t) * TP;
  const unsigned long long* pbr = pb4 + (size_t)(zz >> 3) * TP;
  unsigned long long pt = pbr[t];
  int tid = threadIdx.x;
  float x[3];
  #pragma unroll
  for (int i = 0; i < 3; i++) {
    int s = tid + i * 256;
    bool ok = (pbr[s] & pt) != 0ull;
    x[i] = ok ? __bfloat162float(row[s]) * SCALE_ : -1e30f;
  }
  float mx = fmaxf(fmaxf(x[0], x[1]), x[2]);
  #pragma unroll
  for (int o = 32; o; o >>= 1) mx = fmaxf(mx, __shfl_down(mx, o));
  if ((tid & 63) == 0) red[tid >> 6] = mx;
  __syncthreads();
  mx = fmaxf(fmaxf(red[0], red[1]), fmaxf(red[2], red[3]));
  __syncthreads();
  if (mx <= -1e29f) {  // fully masked row -> nan_to_num -> zeros
    #pragma unroll
    for (int i = 0; i < 3; i++) row[tid + i * 256] = __float2bfloat16(0.f);
    return;
  }
  float e[3], s = 0.f;
  #pragma unroll
  for (int i = 0; i < 3; i++) {
    e[i] = (x[i] <= -1e29f) ? 0.f : __expf(x[i] - mx);
    s += e[i];
  }
  #pragma unroll
  for (int o = 32; o; o >>= 1) s += __shfl_down(s, o);
  if ((tid & 63) == 0) red[tid >> 6] = s;
  __syncthreads();
  s = red[0] + red[1] + red[2] + red[3];
  float inv = 1.f / s;
  #pragma unroll
  for (int i = 0; i < 3; i++) row[tid + i * 256] = __float2bfloat16(e[i] * inv);
}

// batched over z=4 local b: V slice (ld C3) -> Vt4[lb][C_][TP]
__global__ __launch_bounds__(256) void transpose_bt(const bf16* __restrict__ V, bf16* __restrict__ Vt4) {
  __shared__ bf16 tile[32][33];
  int lb = blockIdx.z;
  const bf16* src = V + (size_t)lb * TP * C3;
  bf16* dst = Vt4 + (size_t)lb * C_ * TP;
  int cb = blockIdx.x * 32, tb = blockIdx.y * 32;
  int tx = threadIdx.x & 31, ty = threadIdx.x >> 5;
  #pragma unroll
  for (int i = ty; i < 32; i += 8)
    tile[i][tx] = src[(size_t)(tb + i) * C3 + cb + tx];
  __syncthreads();
  #pragma unroll
  for (int i = ty; i < 32; i += 8)
    dst[(size_t)(cb + i) * TP + tb + tx] = tile[tx][i];
}

// grid (B_*KP, 4): block = (b,k) x 512-c chunk; thread = 2 consecutive c
__global__ __launch_bounds__(256) void seg_pool(const bf16* __restrict__ E, const int* __restrict__ bbox,
                                                const int* __restrict__ cntp, bf16* __restrict__ SEG) {
  int b = blockIdx.x >> 6, k = blockIdx.x & 63;
  int c = (blockIdx.y * 256 + threadIdx.x) * 2;
  int cnt = cntp[b];
  bf16* out = SEG + ((size_t)b * KP + k) * C_ + c;
  if (k >= cnt) {
    out[0] = __float2bfloat16(0.f);
    out[1] = __float2bfloat16(0.f);
    return;
  }
  int s = bbox[(b * K_ + k) * 2], e = bbox[(b * K_ + k) * 2 + 1];
  float inv = 1.f / (float)(e - s + 1);
  const bf16* Ep = E + (size_t)b * TP * C_ + c;
  float a0 = 0.f, a1 = 0.f;
  int t = s;
  for (; t + 3 <= e; t += 4) {
    __hip_bfloat162 v0 = *(const __hip_bfloat162*)(Ep + (size_t)t * C_);
    __hip_bfloat162 v1 = *(const __hip_bfloat162*)(Ep + (size_t)(t + 1) * C_);
    __hip_bfloat162 v2 = *(const __hip_bfloat162*)(Ep + (size_t)(t + 2) * C_);
    __hip_bfloat162 v3 = *(const __hip_bfloat162*)(Ep + (size_t)(t + 3) * C_);
    a0 += __bfloat162float(v0.x) + __bfloat162float(v1.x) + __bfloat162float(v2.x) + __bfloat162float(v3.x);
    a1 += __bfloat162float(v0.y) + __bfloat162float(v1.y) + __bfloat162float(v2.y) + __bfloat162float(v3.y);
  }
  for (; t <= e; t++) {
    __hip_bfloat162 v = *(const __hip_bfloat162*)(Ep + (size_t)t * C_);
    a0 += __bfloat162float(v.x);
    a1 += __bfloat162float(v.y);
  }
  out[0] = __float2bfloat16(a0 * inv);
  out[1] = __float2bfloat16(a1 * inv);
}

// 48 KB LDS; QKV packed [B*KP][C3]: Q at +0, K at +2048, V at +4096
__global__ __launch_bounds__(256) void inter_attn(const bf16* __restrict__ SQKV, const int* __restrict__ cntp,
                                                  bf16* __restrict__ SO) {
  __shared__ bf16 sQ[KP * DH];
  __shared__ float sP[KP * KP];
  int b = blockIdx.x >> 3, h = blockIdx.x & 7;
  int cnt = cntp[b];
  int tid = threadIdx.x;
  size_t base = (size_t)b * KP * C3 + (size_t)h * DH;
  for (int i = tid; i < KP * DH; i += 256) {
    int k = i >> 8, d = i & 255;
    sQ[i] = SQKV[base + (size_t)k * C3 + d];
  }
  __syncthreads();
  for (int p = tid; p < KP * KP; p += 256) {
    int k = p >> 6, kk = p & 63;
    const bf16* Kr = SQKV + base + (size_t)kk * C3 + C_;
    float acc = 0.f;
    for (int d = 0; d < DH; d++)
      acc += __bfloat162float(sQ[k * DH + d]) * __bfloat162float(Kr[d]);
    sP[p] = (k < cnt && kk < cnt) ? acc * SCALE_ : -1e30f;
  }
  __syncthreads();
  if (tid < KP) {
    float* pr = sP + tid * KP;
    if (tid >= cnt) {
      for (int kk = 0; kk < KP; kk++) pr[kk] = 0.f;
    } else {
      float m = -1e30f;
      for (int kk = 0; kk < KP; kk++) m = fmaxf(m, pr[kk]);
      float s = 0.f;
      for (int kk = 0; kk < KP; kk++) {
        float e = (pr[kk] <= -1e29f) ? 0.f : __expf(pr[kk] - m);
        pr[kk] = e; s += e;
      }
      float inv = 1.f / s;
      for (int kk = 0; kk < KP; kk++) pr[kk] *= inv;
    }
  }
  __syncthreads();
  for (int i = tid; i < KP * DH; i += 256) {  // reuse sQ for V
    int k = i >> 8, d = i & 255;
    sQ[i] = SQKV[base + (size_t)k * C3 + 2 * C_ + d];
  }
  __syncthreads();
  for (int i = tid; i < KP * DH; i += 256) {
    int k = i >> 8, d = i & 255;
    float acc = 0.f;
    for (int kk = 0; kk < KP; kk++)
      acc += sP[k * KP + kk] * __bfloat162float(sQ[kk * DH + d]);
    SO[((size_t)b * KP + k) * C_ + (size_t)h * DH + d] = __float2bfloat16(acc);
  }
}

__global__ __launch_bounds__(256) void scatter_seg(const bf16* __restrict__ SO, const int* __restrict__ bbox,
                                                   const int* __restrict__ cntp, const float* __restrict__ rcnt,
                                                   bf16* __restrict__ OUTG) {
  __shared__ int klist[K_];
  __shared__ int nk;
  int b = blockIdx.x / TP, t = blockIdx.x % TP;
  int cnt = cntp[b];
  if (threadIdx.x == 0) {
    int n = 0;
    for (int k = 0; k < cnt; k++) {
      int s = bbox[(b * K_ + k) * 2], e = bbox[(b * K_ + k) * 2 + 1];
      if (s <= t && t <= e) klist[n++] = k;
    }
    nk = n;
  }
  __syncthreads();
  float inv = 1.f / fmaxf(rcnt[b * TP + t], 1e-5f);
  const bf16* Sb = SO + (size_t)b * KP * C_;
  bf16* out = OUTG + ((size_t)b * TP + t) * C_;
  int n = nk;
  for (int c = threadIdx.x; c < C_; c += 256) {
    float acc = 0.f;
    for (int i = 0; i < n; i++) acc += __bfloat162float(Sb[(size_t)klist[i] * C_ + c]);
    out[c] = __float2bfloat16(acc * inv);
  }
}

__global__ __launch_bounds__(256) void heads(const bf16* __restrict__ E,
    const float* __restrict__ att_w, const float* __restrict__ att_b,
    const float* __restrict__ cls_w, const float* __restrict__ cls_b,
    const float* __restrict__ unc_w,
    float* __restrict__ fgc, float* __restrict__ bgc, float* __restrict__ out) {
  __shared__ float part[24][4];
  int b = blockIdx.x / T_, t = blockIdx.x % T_;
  int tid = threadIdx.x, lane = tid & 63, wv = tid >> 6;
  const bf16* e = E + ((size_t)b * TP + t) * C_;
  int c0 = tid * 8;
  float vals[24];
  #pragma unroll
  for (int o = 0; o < 24; o++) vals[o] = 0.f;
  #pragma unroll
  for (int i = 0; i < 8; i++) {
    float x = __bfloat162float(e[c0 + i]);
    vals[0] += x * att_w[c0 + i];
    vals[1] += x * att_w[C_ + c0 + i];
    vals[2] += x * unc_w[c0 + i];
    #pragma unroll
    for (int o = 0; o < NCLS; o++)
      vals[3 + o] += x * cls_w[(size_t)(c0 + i) * NCLS + o];
  }
  #pragma unroll
  for (int o = 0; o < 24; o++) {
    float v = vals[o];
    #pragma unroll
    for (int off = 32; off; off >>= 1) v += __shfl_down(v, off);
    if (lane == 0) part[o][wv] = v;
  }
  __syncthreads();
  if (tid == 0) {
    float s[24];
    #pragma unroll
    for (int o = 0; o < 24; o++) s[o] = part[o][0] + part[o][1] + part[o][2] + part[o][3];
    size_t bt = (size_t)b * T_ + t;
    float v0 = s[0] + att_b[0];
    float v1 = s[1] + att_b[1];
    float m = fmaxf(v0, v1);
    float e0 = __expf(v0 - m), e1 = __expf(v1 - m);
    float p0 = e0 / (e0 + e1), p1 = e1 / (e0 + e1);
    out[O_ATT + bt * 2]     = p0;
    out[O_ATT + bt * 2 + 1] = p1;
    out[O_UNC + bt]         = s[2];
    float cas[NCLS], fg[NCLS], bg[NCLS];
    for (int o = 0; o < NCLS; o++) {
      cas[o] = s[3 + o] + cls_b[o];
      fg[o] = cas[o] * p0;
      bg[o] = cas[o] * p1;
      fgc[bt * NCLS + o] = fg[o];
      bgc[bt * NCLS + o] = bg[o];
    }
    auto smax = [&](const float* v, float* dst) {
      float mm = v[0];
      for (int o = 1; o < NCLS; o++) mm = fmaxf(mm, v[o]);
      float ss = 0.f; float ee[NCLS];
      for (int o = 0; o < NCLS; o++) { ee[o] = __expf(v[o] - mm); ss += ee[o]; }
      float iv = 1.f / ss;
      for (int o = 0; o < NCLS; o++) dst[o] = ee[o] * iv;
    };
    smax(cas, out + O_CAS + bt * NCLS);
    smax(fg,  out + O_FGC + bt * NCLS);
    smax(bg,  out + O_BGC + bt * NCLS);
  }
}

// bitonic sort descending; arr[0..ksel) are the largest
__global__ __launch_bounds__(512) void topk_mean(const float* __restrict__ fgc, const float* __restrict__ bgc,
                                                 float* __restrict__ means) {
  __shared__ float arr[1024];
  __shared__ float red[8];
  int idx = blockIdx.x;
  int which = idx / (B_ * NCLS);
  int r = idx % (B_ * NCLS);
  int b = r / NCLS, n = r % NCLS;
  const float* src = which ? bgc : fgc;
  int ksel = which ? BG_TOPK : FG_TOPK;
  int tid = threadIdx.x;
  for (int i = tid; i < 1024; i += 512)
    arr[i] = (i < T_) ? src[((size_t)b * T_ + i) * NCLS + n] : -1e30f;
  __syncthreads();
  for (int k = 2; k <= 1024; k <<= 1)
    for (int j = k >> 1; j > 0; j >>= 1) {
      for (int i = tid; i < 1024; i += 512) {
        int ixj = i ^ j;
        if (ixj > i) {
          bool up = ((i & k) == 0);
          float x = arr[i], y = arr[ixj];
          if (up ? (x < y) : (x > y)) { arr[i] = y; arr[ixj] = x; }
        }
      }
      __syncthreads();
    }
  float s = 0.f;
  for (int i = tid; i < ksel; i += 512) s += arr[i];
  #pragma unroll
  for (int o = 32; o; o >>= 1) s += __shfl_down(s, o);
  if ((tid & 63) == 0) red[tid >> 6] = s;
  __syncthreads();
  if (tid == 0) {
    float tot = 0.f;
    for (int w = 0; w < 8; w++) tot += red[w];
    means[(which * B_ + b) * NCLS + n] = tot / (float)ksel;
  }
}

__global__ void final_cls(const float* __restrict__ means, float* __restrict__ out) {
  if (threadIdx.x != 0) return;
  int which = blockIdx.x >> 4, b = blockIdx.x & 15;
  const float* v = means + (which * B_ + b) * NCLS;
  float m = v[0];
  for (int o = 1; o < NCLS; o++) m = fmaxf(m, v[o]);
  float s = 0.f; float e[NCLS];
  for (int o = 0; o < NCLS; o++) { e[o] = __expf(v[o] - m); s += e[o]; }
  float iv = 1.f / s;
  float* dst = out + (which ? O_BG : O_FG) + b * NCLS;
  for (int o = 0; o < NCLS; o++) dst[o] = e[o] * iv;
}

extern "C" void kernel_launch(void* const* d_in, const int* in_sizes, int n_in,
                              void* d_out, int out_size, void* d_ws, size_t ws_size,
                              hipStream_t stream) {
  const float* X     = (const float*)d_in[0];
  const int*   bbox  = (const int*)d_in[1];
  const int*   cntp  = (const int*)d_in[2];
  const float* emb_w = (const float*)d_in[3];
  const float* emb_b = (const float*)d_in[4];
  const float* i_qw  = (const float*)d_in[5];
  const float* i_qb  = (const float*)d_in[6];
  const float* i_kw  = (const float*)d_in[7];
  const float* i_kb  = (const float*)d_in[8];
  const float* i_vw  = (const float*)d_in[9];
  const float* i_vb  = (const float*)d_in[10];
  const float* i_ow  = (const float*)d_in[11];
  const float* i_ob  = (const float*)d_in[12];
  const float* i_bng = (const float*)d_in[13];
  const float* i_bnb = (const float*)d_in[14];
  const float* i_bnm = (const float*)d_in[15];
  const float* i_bnv = (const float*)d_in[16];
  const float* e_qw  = (const float*)d_in[17];
  const float* e_qb  = (const float*)d_in[18];
  const float* e_kw  = (const float*)d_in[19];
  const float* e_kb  = (const float*)d_in[20];
  const float* e_vw  = (const float*)d_in[21];
  const float* e_vb  = (const float*)d_in[22];
  const float* e_ow  = (const float*)d_in[23];
  const float* e_ob  = (const float*)d_in[24];
  const float* e_bng = (const float*)d_in[25];
  const float* e_bnb = (const float*)d_in[26];
  const float* e_bnm = (const float*)d_in[27];
  const float* e_bnv = (const float*)d_in[28];
  const float* att_w = (const float*)d_in[29];
  const float* att_b = (const float*)d_in[30];
  const float* cls_w = (const float*)d_in[31];
  const float* cls_b = (const float*)d_in[32];
  const float* unc_w = (const float*)d_in[33];
  float* out = (float*)d_out;

  // -------- workspace layout (lifetime-aliased, total 197,263,360 B) --------
  const size_t SZ_E  = (size_t)B_ * TP * C_ * 2;   // 50,331,648
  const size_t SZ_A  = (size_t)B_ * 770 * C_ * 2;  // 50,462,720  Xc -> SIM4+O4 -> OUTG
  const size_t SZ_W  = (size_t)C_ * 3 * C_ * 2;    // 25,165,824  Wcv -> Vt4/pb/rcnt/means/biases -> fgc/bgc
  const size_t SZ_P  = (size_t)4 * C_ * C_ * 2;    // 33,554,432  bf16 proj weights (i_, then e_)
  const size_t SZ_QKV= (size_t)4 * TP * C3 * 2;    // 37,748,736  quarter QKV -> SEG/SQKV/SOb
  const size_t NEED  = SZ_E + SZ_A + SZ_W + SZ_P + SZ_QKV;
  if (ws_size < NEED) return;   // diagnostic: out stays zero

  char* ws  = (char*)d_ws;
  bf16* E   = (bf16*)ws;
  char* rA  = ws + SZ_E;
  char* rW  = rA + SZ_A;
  char* rP  = rW + SZ_W;
  char* rQKV= rP + SZ_P;

  // rA: conv input -> attention score/output -> scatter output
  bf16* Xc   = (bf16*)rA;
  bf16* SIM4 = (bf16*)rA;                      // 37,748,736
  bf16* O4   = (bf16*)(rA + 37748736);         // 12,582,912
  bf16* OUTG = (bf16*)rA;
  // rW: conv weight -> attention aux -> head scratch
  bf16* Wcv  = (bf16*)rW;
  bf16* Vt4  = (bf16*)rW;                                         // 12,582,912
  unsigned long long* pb = (unsigned long long*)(rW + 12582912);  // 98,304
  float* rcnt   = (float*)(rW + 12681216);                        // 49,152
  float* means  = (float*)(rW + 12730368);                        // 2,688
  float* qkvb_i = (float*)(rW + 12733056);                        // 24,576
  float* qkvb_e = (float*)(rW + 12757632);                        // 24,576
  float* fgc = (float*)rW;                     // after attention (Vt4 dead)
  float* bgc = (float*)(rW + 1048576);
  // rP: 4 bf16 weight slots (Wq,Wk,Wv contiguous = one [C3][C_] matrix)
  bf16* Wq = (bf16*)rP;
  bf16* Wk = Wq + (size_t)C_ * C_;
  bf16* Wv = Wk + (size_t)C_ * C_;
  bf16* Wo = Wv + (size_t)C_ * C_;
  // rQKV: quarter QKV -> inter-segment buffers
  bf16* QKV4 = (bf16*)rQKV;
  bf16* SEG  = (bf16*)rQKV;                               // 2,097,152
  bf16* SQKV = SEG + (size_t)B_ * KP * C_;                // 12,582,912
  bf16* SOb  = SQKV + (size_t)B_ * KP * C3;               // 4,194,304

  const long long ZC = (long long)TP * C_;
  const long long ZS = (long long)TP * TP;
  const int NW = C_ * C_;

  pack_wconv<<<dim3((C_ * 3 * C_) / 256), 256, 0, stream>>>(emb_w, Wcv);
  pack_xc<<<dim3((B_ * 770 * C_) / 256), 256, 0, stream>>>(X, Xc);

  // emb = relu(conv1d(x) + b)   [Xc, Wcv die here]
  gemm_nt<EPI_BIAS_RELU, 1><<<dim3(C_ / 128, (B_ * TP) / 128, 1), 256, 0, stream>>>(
      Xc, C_, 0, 0, Wcv, 3 * C_, 0, 0, E, C_, 0, 0, 3 * C_, 1, emb_b, nullptr, nullptr, nullptr, nullptr);

  mask_kernel<<<dim3(B_), 256, 0, stream>>>(bbox, cntp, pb, rcnt);
  concat3<<<dim3(C_ / 256), 256, 0, stream>>>(i_qb, i_kb, i_vb, qkvb_i);
  concat3<<<dim3(C_ / 256), 256, 0, stream>>>(e_qb, e_kb, e_vb, qkvb_e);

  // convert intra projection weights f32 -> bf16
  cvt_f32_bf16<<<dim3(NW / 1024), 256, 0, stream>>>(i_qw, Wq, NW);
  cvt_f32_bf16<<<dim3(NW / 1024), 256, 0, stream>>>(i_kw, Wk, NW);
  cvt_f32_bf16<<<dim3(NW / 1024), 256, 0, stream>>>(i_vw, Wv, NW);
  cvt_f32_bf16<<<dim3(NW / 1024), 256, 0, stream>>>(i_ow, Wo, NW);

  // intra attention: per quarter (4 b's), fused QKV + batched heads (z=32)
  for (int q4 = 0; q4 < 4; q4++) {
    const bf16* Eq = E + (size_t)q4 * 4 * ZC;
    // fused QKV: [3072, 2048] x [6144, 2048]^T -> QKV4 [3072][6144]
    gemm_nt<EPI_BIAS, 0><<<dim3(C3 / 128, (4 * TP) / 128, 1), 256, 0, stream>>>(
        Eq, C_, 0, 0, Wq, C_, 0, 0, QKV4, C3, 0, 0, C_, 1, qkvb_i, nullptr, nullptr, nullptr, nullptr);
    // V slices -> Vt4[lb][C_][TP]
    transpose_bt<<<dim3(C_ / 32, TP / 32, 4), 256, 0, stream>>>(QKV4 + 2 * C_, Vt4);
    // scores: z = lb*8+h
    gemm_nt<EPI_RAW, 0><<<dim3(TP / 128, TP / 128, 32), 256, 0, stream>>>(
        QKV4, C3, (long long)TP * C3, DH, QKV4 + C_, C3, (long long)TP * C3, DH,
        SIM4, TP, 8 * ZS, ZS, DH, 8, nullptr, nullptr, nullptr, nullptr, nullptr);
    softmax_intra<<<dim3(32 * TP), 256, 0, stream>>>(SIM4, pb + (size_t)q4 * 4 * TP);
    // O4 = P V
    gemm_nt<EPI_RAW, 0><<<dim3(DH / 128, TP / 128, 32), 256, 0, stream>>>(
        SIM4, TP, 8 * ZS, ZS, Vt4, TP, (long long)C_ * TP, (long long)DH * TP,
        O4, C_, ZC, DH, TP, 8, nullptr, nullptr, nullptr, nullptr, nullptr);
    // E[q] += BN(O4 @ i_ow^T + i_ob)
    gemm_nt<EPI_BN, 0><<<dim3(C_ / 128, (4 * TP) / 128, 1), 256, 0, stream>>>(
        O4, C_, 0, 0, Wo, C_, 0, 0, E + (size_t)q4 * 4 * ZC, C_, 0, 0, C_, 1,
        i_ob, i_bng, i_bnb, i_bnm, i_bnv);
  }

  // convert inter projection weights f32 -> bf16 (reuse slots)
  cvt_f32_bf16<<<dim3(NW / 1024), 256, 0, stream>>>(e_qw, Wq, NW);
  cvt_f32_bf16<<<dim3(NW / 1024), 256, 0, stream>>>(e_kw, Wk, NW);
  cvt_f32_bf16<<<dim3(NW / 1024), 256, 0, stream>>>(e_vw, Wv, NW);
  cvt_f32_bf16<<<dim3(NW / 1024), 256, 0, stream>>>(e_ow, Wo, NW);

  // inter-segment branch
  seg_pool<<<dim3(B_ * KP, 4), 256, 0, stream>>>(E, bbox, cntp, SEG);
  gemm_nt<EPI_BIAS, 0><<<dim3(C3 / 128, (B_ * KP) / 128, 1), 256, 0, stream>>>(
      SEG, C_, 0, 0, Wq, C_, 0, 0, SQKV, C3, 0, 0, C_, 1, qkvb_e, nullptr, nullptr, nullptr, nullptr);
  inter_attn<<<dim3(B_ * H_), 256, 0, stream>>>(SQKV, cntp, SOb);
  scatter_seg<<<dim3(B_ * TP), 256, 0, stream>>>(SOb, bbox, cntp, rcnt, OUTG);
  gemm_nt<EPI_BN, 0><<<dim3(C_ / 128, (B_ * TP) / 128, 1), 256, 0, stream>>>(
      OUTG, C_, 0, 0, Wo, C_, 0, 0, E, C_, 0, 0, C_, 1, e_ob, e_bng, e_bnb, e_bnm, e_bnv);

  // heads + top-k + class softmaxes  [Vt4 region -> fgc/bgc]
  heads<<<dim3(B_ * T_), 256, 0, stream>>>(E, att_w, att_b, cls_w, cls_b, unc_w, fgc, bgc, out);
  topk_mean<<<dim3(2 * B_ * NCLS), 512, 0, stream>>>(fgc, bgc, means);
  final_cls<<<dim3(2 * B_), 64, 0, stream>>>(means, out);

  (void)in_sizes; (void)n_in; (void)out_size;
}